// Round 1
// 1571.112 us; speedup vs baseline: 1.2019x; 1.2019x over previous
//
#include <hip/hip_runtime.h>
#include <stdint.h>

// ---------------- problem constants ----------------
constexpr int Lc  = 197;
constexpr int Nc  = 128;
constexpr int Ec  = 768;
constexpr int HDc = 64;
constexpr int Bc  = Nc * 12;        // 1536 batch*heads
constexpr int LTc = Lc + 60;        // 257 output rows
constexpr float EPSc = 1e-12f;

// ---------------- threefry2x32 (JAX-exact, partitionable variant) ----------------
struct U2 { uint32_t x, y; };

__device__ __forceinline__ U2 tf2x32(uint32_t k0, uint32_t k1, uint32_t x0, uint32_t x1) {
  uint32_t k2 = k0 ^ k1 ^ 0x1BD11BDAu;
  x0 += k0; x1 += k1;
#define TFR(r) { x0 += x1; x1 = (x1 << (r)) | (x1 >> (32 - (r))); x1 ^= x0; }
  TFR(13) TFR(15) TFR(26) TFR(6)
  x0 += k1; x1 += k2 + 1u;
  TFR(17) TFR(29) TFR(16) TFR(24)
  x0 += k2; x1 += k0 + 2u;
  TFR(13) TFR(15) TFR(26) TFR(6)
  x0 += k0; x1 += k1 + 3u;
  TFR(17) TFR(29) TFR(16) TFR(24)
  x0 += k1; x1 += k2 + 4u;
  TFR(13) TFR(15) TFR(26) TFR(6)
  x0 += k2; x1 += k0 + 5u;
#undef TFR
  return {x0, x1};
}

__device__ __forceinline__ float u01f(uint32_t bits) {
  return __uint_as_float((bits >> 9) | 0x3f800000u) - 1.0f;
}

__device__ __forceinline__ uint32_t rbits(uint32_t ka, uint32_t kb, uint32_t idx) {
  U2 r = tf2x32(ka, kb, 0u, idx);
  return r.x ^ r.y;
}

__device__ __forceinline__ void split_keys(uint32_t& k1a, uint32_t& k1b, uint32_t& k2a, uint32_t& k2b) {
  U2 t0 = tf2x32(0u, 1234u, 0u, 0u); k1a = t0.x; k1b = t0.y;
  U2 t1 = tf2x32(0u, 1234u, 0u, 1u); k2a = t1.x; k2b = t1.y;
}

// wave-uniform lane broadcast: VALU readlane (no LDS pipe, no lgkm wait)
__device__ __forceinline__ float rdlane(float v, int l) {
  return __int_as_float(__builtin_amdgcn_readlane(__float_as_int(v), l));
}

// ---------------- fp32 -> bf16 hi/lo split (trunc hi + exact residual) ----------------
__device__ __forceinline__ void f2hilo(float f, unsigned short& h, unsigned short& l) {
  uint32_t u = __float_as_uint(f);
  h = (unsigned short)(u >> 16);
  float lof = f - __uint_as_float(u & 0xffff0000u);
  l = (unsigned short)(__float_as_uint(lof) >> 16);
}

// src: rows x 768 fp32, dst: rows x 1536 bf16 (cols 0..767 = hi, 768..1535 = lo)
__global__ __launch_bounds__(256) void convert_hilo(const float* __restrict__ src,
                                                    unsigned short* __restrict__ dst,
                                                    int rows)
{
  int idx = blockIdx.x * 256 + threadIdx.x;   // one float4 per thread
  int total = rows * 192;
  if (idx >= total) return;
  int m = idx / 192, c = (idx % 192) * 4;
  float4 f = *(const float4*)(src + (size_t)m * 768 + c);
  ushort4 hv, lv;
  f2hilo(f.x, hv.x, lv.x);
  f2hilo(f.y, hv.y, lv.y);
  f2hilo(f.z, hv.z, lv.z);
  f2hilo(f.w, hv.w, lv.w);
  *(ushort4*)(dst + (size_t)m * 1536 + c) = hv;
  *(ushort4*)(dst + (size_t)m * 1536 + 768 + c) = lv;
}

// ---------------- MFMA bf16 GEMM: C = A(bf16 hi|lo, MxK=1536) @ Wb^T + bias ----------------
typedef __attribute__((ext_vector_type(8))) short bfrag_t;
typedef __attribute__((ext_vector_type(4))) float accfrag_t;

template <int MODE>
__global__ __launch_bounds__(256) void gemm_mfma(
    const unsigned short* __restrict__ A0, const unsigned short* __restrict__ A1,
    const unsigned short* __restrict__ A2in, const unsigned short* __restrict__ Wb,
    const float* __restrict__ bias, int cb,
    float* __restrict__ O0, float* __restrict__ O1, float* __restrict__ O2)
{
  __shared__ unsigned short As[128 * 40];   // stride 40 bf16 = 80 B -> 2-way max on b128 frag reads
  __shared__ unsigned short Bs[128 * 40];
  const int bm = blockIdx.x;
  const int bn = cb + blockIdx.y;
  const int tid = threadIdx.x;
  const int lane = tid & 63, wv = tid >> 6;
  const int wm = (wv & 1) * 64, wn = (wv >> 1) * 64;
  const int q4 = lane >> 4, l16 = lane & 15;

  const unsigned short* A;
  int which = 0;
  if (MODE == 0) { which = bn / 6; A = which == 0 ? A0 : (which == 1 ? A1 : A2in); }
  else A = A0;

  const int sr = tid >> 2;           // staging row within 64-row half
  const int sc = (tid & 3) * 8;      // staging col (8 bf16 = 16 B)

  accfrag_t acc[4][4];
#pragma unroll
  for (int i = 0; i < 4; i++)
#pragma unroll
    for (int j = 0; j < 4; j++)
#pragma unroll
      for (int r = 0; r < 4; r++) acc[i][j][r] = 0.0f;

  for (int kt = 0; kt < 48; kt++) {
    const int k0 = kt * 32;
    __syncthreads();
#pragma unroll
    for (int p = 0; p < 2; p++) {
      int r = p * 64 + sr;
      uint4 av = *(const uint4*)(A  + (size_t)(bm * 128 + r) * 1536 + k0 + sc);
      *(uint4*)&As[r * 40 + sc] = av;
      uint4 bv = *(const uint4*)(Wb + (size_t)(bn * 128 + r) * 1536 + k0 + sc);
      *(uint4*)&Bs[r * 40 + sc] = bv;
    }
    __syncthreads();
    bfrag_t af[4], bf[4];
#pragma unroll
    for (int i = 0; i < 4; i++) {
      af[i] = *(const bfrag_t*)&As[(wm + i * 16 + l16) * 40 + q4 * 8];
      bf[i] = *(const bfrag_t*)&Bs[(wn + i * 16 + l16) * 40 + q4 * 8];
    }
#pragma unroll
    for (int i = 0; i < 4; i++)
#pragma unroll
      for (int j = 0; j < 4; j++)
        acc[i][j] = __builtin_amdgcn_mfma_f32_16x16x32_bf16(af[i], bf[j], acc[i][j], 0, 0, 0);
  }

  float bv4[4];
#pragma unroll
  for (int j = 0; j < 4; j++) bv4[j] = bias[bn * 128 + wn + j * 16 + l16];

  if (MODE == 0) {
    const float scale = (which == 0) ? 0.125f : 1.0f;
    float* O = which == 0 ? O0 : (which == 1 ? O1 : O2);
#pragma unroll
    for (int i = 0; i < 4; i++) {
#pragma unroll
      for (int r = 0; r < 4; r++) {
        int m = bm * 128 + wm + i * 16 + q4 * 4 + r;   // m = l*128 + n
        int l = m >> 7, nb = m & 127;
#pragma unroll
        for (int j = 0; j < 4; j++) {
          int ng = bn * 128 + wn + j * 16 + l16;
          int nc = ng - which * 768;
          int h = nc >> 6, d = nc & 63;
          O[(((size_t)(nb * 12 + h)) * 197 + l) * 64 + d] = (acc[i][j][r] + bv4[j]) * scale;
        }
      }
    }
  } else {
#pragma unroll
    for (int i = 0; i < 4; i++) {
#pragma unroll
      for (int r = 0; r < 4; r++) {
        int m = bm * 128 + wm + i * 16 + q4 * 4 + r;
#pragma unroll
        for (int j = 0; j < 4; j++) {
          int ng = bn * 128 + wn + j * 16 + l16;
          O0[(size_t)m * 768 + ng] = acc[i][j][r] + bv4[j];
        }
      }
    }
  }
}

// ---------------- K2: center row (= S[b,0,:]) and its norm ----------------
__global__ __launch_bounds__(256) void center_kernel(
    const float* __restrict__ q_ws, const float* __restrict__ k_ws,
    float* __restrict__ center, float* __restrict__ cnorm)
{
  const int b = blockIdx.x;
  const int lane = threadIdx.x & 63, w = threadIdx.x >> 6;
  __shared__ float ssh[4];
  const float q0 = q_ws[(size_t)b * (197 * 64) + lane];
  float ss = 0.0f;
  for (int s = w; s < 197; s += 4) {
    float val = q0 * k_ws[((size_t)b * 197 + s) * 64 + lane];
#pragma unroll
    for (int off = 32; off >= 1; off >>= 1) val += __shfl_xor(val, off, 64);
    if (lane == 0) center[(size_t)b * 197 + s] = val;
    ss += val * val;
  }
  if (lane == 0) ssh[w] = ss;
  __syncthreads();
  if (threadIdx.x == 0) cnorm[b] = sqrtf(ssh[0] + ssh[1] + ssh[2] + ssh[3]);
}

// ---------------- K3 helpers ----------------
__device__ __forceinline__ void softmax_row(float x0, float x1, float x2, float x3,
                                            bool v3, float* p)
{
  float m = fmaxf(fmaxf(x0, x1), x2);
  if (v3) m = fmaxf(m, x3);
#pragma unroll
  for (int off = 32; off >= 1; off >>= 1) m = fmaxf(m, __shfl_xor(m, off, 64));
  float e0 = __expf(x0 - m), e1 = __expf(x1 - m), e2 = __expf(x2 - m);
  float e3 = v3 ? __expf(x3 - m) : 0.0f;
  float s = e0 + e1 + e2 + e3;
#pragma unroll
  for (int off = 32; off >= 1; off >>= 1) s += __shfl_xor(s, off, 64);
  float rs = 1.0f / s;
  p[0] = e0 * rs; p[1] = e1 * rs; p[2] = e2 * rs; p[3] = e3 * rs;
}

// batched 4-row softmax: the 4 rows' reduction chains interleave (latency /4)
__device__ __forceinline__ void softmax4(float x[4][4], bool v3, float p[4][4])
{
  float m[4], s[4];
#pragma unroll
  for (int i = 0; i < 4; i++) {
    m[i] = fmaxf(fmaxf(x[i][0], x[i][1]), x[i][2]);
    if (v3) m[i] = fmaxf(m[i], x[i][3]);
  }
#pragma unroll
  for (int off = 32; off >= 1; off >>= 1) {
#pragma unroll
    for (int i = 0; i < 4; i++) m[i] = fmaxf(m[i], __shfl_xor(m[i], off, 64));
  }
#pragma unroll
  for (int i = 0; i < 4; i++) {
    float e0 = __expf(x[i][0] - m[i]);
    float e1 = __expf(x[i][1] - m[i]);
    float e2 = __expf(x[i][2] - m[i]);
    float e3 = v3 ? __expf(x[i][3] - m[i]) : 0.0f;
    p[i][0] = e0; p[i][1] = e1; p[i][2] = e2; p[i][3] = e3;
    s[i] = e0 + e1 + e2 + e3;
  }
#pragma unroll
  for (int off = 32; off >= 1; off >>= 1) {
#pragma unroll
    for (int i = 0; i < 4; i++) s[i] += __shfl_xor(s[i], off, 64);
  }
#pragma unroll
  for (int i = 0; i < 4; i++) {
    float rs = 1.0f / s[i];
    p[i][0] *= rs; p[i][1] *= rs; p[i][2] *= rs; p[i][3] *= rs;
  }
}

__device__ __forceinline__ void weights_add(float* __restrict__ awn, int t, int lane,
                                            bool v3, const float* p)
{
  float* a = awn + (size_t)t * 197;
  const float c = 1.0f / 12.0f;
  atomicAdd(a + lane, p[0] * c);
  atomicAdd(a + lane + 64, p[1] * c);
  atomicAdd(a + lane + 128, p[2] * c);
  if (v3) atomicAdd(a + lane + 192, p[3] * c);
}

// PV for 4 rows: o[d=lane] = sum_s p[s] * v[s][d]; broadcast via readlane (VALU, not LDS pipe).
__device__ __forceinline__ void pv_store4(const float* __restrict__ vg, float p[4][4],
                                          int t0, int nval, int n, int h, int lane,
                                          unsigned short* __restrict__ A2)
{
  float o[4] = {0.0f, 0.0f, 0.0f, 0.0f};
#pragma unroll
  for (int j = 0; j < 4; j++) {
    const int send = (j < 3) ? 64 : 5;   // 197 = 3*64 + 5
#pragma unroll 4
    for (int si = 0; si < send; si++) {
      const int s = j * 64 + si;
      float vv = vg[(size_t)s * 64 + lane];
      o[0] = fmaf(rdlane(p[0][j], si), vv, o[0]);
      o[1] = fmaf(rdlane(p[1][j], si), vv, o[1]);
      o[2] = fmaf(rdlane(p[2][j], si), vv, o[2]);
      o[3] = fmaf(rdlane(p[3][j], si), vv, o[3]);
    }
  }
#pragma unroll
  for (int i = 0; i < 4; i++) {
    if (i < nval) {
      unsigned short hb, lb;
      f2hilo(o[i], hb, lb);
      size_t base = ((size_t)(t0 + i) * 128 + n) * 1536 + h * 64 + lane;
      A2[base] = hb;
      A2[base + 768] = lb;
    }
  }
}

// ---------------- K3: fused scores + RNG rows + softmax + PV + weights ----------------
// LDS = kT(51456) + cen(800) + uu(800) = 53056 B -> 3 blocks/CU (24 waves).
// launch_bounds(512,6): cap VGPRs at ~84 so occupancy stays LDS-limited, not VGPR-limited.
__global__ __launch_bounds__(512, 6) void attn_kernel(
    const float* __restrict__ q_ws, const float* __restrict__ k_ws, const float* __restrict__ v_ws,
    const float* __restrict__ center, const float* __restrict__ cnorm,
    unsigned short* __restrict__ A2, float* __restrict__ attn_w)
{
  __shared__ float kT[64][201];     // 201: staging banks (9d+s)%32 -> 2-way max; frag reads conflict-free
  __shared__ float cen[200];
  __shared__ float uu[200];

  const int b = blockIdx.x;
  const int n = b / 12, h = b % 12;
  const int tid = threadIdx.x;
  const int lane = tid & 63, w = tid >> 6;
  const bool v3 = lane < 5;

  const float* kg = k_ws + (size_t)b * (197 * 64);
  const float* vg = v_ws + (size_t)b * (197 * 64);
  const float* qg = q_ws + (size_t)b * (197 * 64);

  for (int idx = tid; idx < 197 * 64; idx += 512)
    kT[idx & 63][idx >> 6] = kg[idx];
  {
    float inv = 1.0f / fmaxf(cnorm[b], EPSc);
    for (int s = tid; s < 197; s += 512) {
      float c = center[(size_t)b * 197 + s];
      cen[s] = c;
      uu[s] = c * inv;
    }
  }
  __syncthreads();

  // per-lane-constant unit-center components: load ONCE per block
  const float us0 = uu[lane], us1 = uu[lane + 64], us2 = uu[lane + 128];
  const float us3 = v3 ? uu[lane + 192] : 0.0f;

  const float cnb = cnorm[b];
  uint32_t k1a, k1b, k2a, k2b;
  split_keys(k1a, k1b, k2a, k2b);
  float* awn = attn_w + (size_t)n * (LTc * 197);

  // ---- rows 0..60 in 16 groups of 4 (group 15: only t=60 valid) ----
  for (int g = w; g < 16; g += 8) {
    const int t0 = g * 4;
    const int nval = (g == 15) ? 1 : 4;
    float pr[4][4];
#pragma unroll
    for (int i = 0; i < 4; i++) {
      if (i >= nval) { pr[i][0] = pr[i][1] = pr[i][2] = pr[i][3] = 0.0f; continue; }
      const int t = t0 + i;
      float x0, x1, x2, x3;
      if (t == 0) {
        x0 = cen[lane]; x1 = cen[lane + 64]; x2 = cen[lane + 128];
        x3 = v3 ? cen[lane + 192] : 0.0f;
      } else {
        const int ns = t - 1;
        const uint32_t base = ((uint32_t)ns * 1536u + (uint32_t)b) * 197u;
        float r0 = u01f(rbits(k1a, k1b, base + lane))       * 2.0f - 1.0f;
        float r1 = u01f(rbits(k1a, k1b, base + lane + 64))  * 2.0f - 1.0f;
        float r2 = u01f(rbits(k1a, k1b, base + lane + 128)) * 2.0f - 1.0f;
        float r3 = v3 ? (u01f(rbits(k1a, k1b, base + lane + 192)) * 2.0f - 1.0f) : 0.0f;
        float pa = r0 * us0 + r1 * us1 + r2 * us2 + r3 * us3;
#pragma unroll
        for (int off = 32; off >= 1; off >>= 1) pa += __shfl_xor(pa, off, 64);
        float rp0 = r0 - pa * us0, rp1 = r1 - pa * us1;
        float rp2 = r2 - pa * us2, rp3 = r3 - pa * us3;
        float sq2 = rp0 * rp0 + rp1 * rp1 + rp2 * rp2 + (v3 ? rp3 * rp3 : 0.0f);
#pragma unroll
        for (int off = 32; off >= 1; off >>= 1) sq2 += __shfl_xor(sq2, off, 64);
        float invn = 1.0f / fmaxf(sqrtf(sq2), EPSc);
        float cv = u01f(rbits(k2a, k2b, (uint32_t)ns)) * 0.2f + 0.7f;
        float sv = sqrtf(1.0f - cv * cv);
        float f = sv * invn;
        x0 = cnb * (cv * us0 + f * rp0);
        x1 = cnb * (cv * us1 + f * rp1);
        x2 = cnb * (cv * us2 + f * rp2);
        x3 = cnb * (cv * us3 + f * rp3);
      }
      softmax_row(x0, x1, x2, x3, v3, pr[i]);
      weights_add(awn, t, lane, v3, pr[i]);
    }
    pv_store4(vg, pr, t0, nval, n, h, lane, A2);
  }

  // ---- rows 61..256: 49 four-row batches, register-tiled q @ kT ----
  for (int bi = w; bi < 49; bi += 8) {
    const int t0 = 61 + bi * 4;
    const int l0 = t0 - 60;
    float qr[4];
#pragma unroll
    for (int i = 0; i < 4; i++)
      qr[i] = qg[(size_t)(l0 + i) * 64 + lane];

    float acc[4][4] = {};
#pragma unroll 4
    for (int d = 0; d < 64; d++) {
      float q0 = rdlane(qr[0], d), q1 = rdlane(qr[1], d);
      float q2 = rdlane(qr[2], d), q3 = rdlane(qr[3], d);
      float kv0 = kT[d][lane], kv1 = kT[d][lane + 64], kv2 = kT[d][lane + 128];
      float kv3 = v3 ? kT[d][lane + 192] : 0.0f;
      acc[0][0] = fmaf(q0, kv0, acc[0][0]); acc[0][1] = fmaf(q0, kv1, acc[0][1]);
      acc[0][2] = fmaf(q0, kv2, acc[0][2]); acc[0][3] = fmaf(q0, kv3, acc[0][3]);
      acc[1][0] = fmaf(q1, kv0, acc[1][0]); acc[1][1] = fmaf(q1, kv1, acc[1][1]);
      acc[1][2] = fmaf(q1, kv2, acc[1][2]); acc[1][3] = fmaf(q1, kv3, acc[1][3]);
      acc[2][0] = fmaf(q2, kv0, acc[2][0]); acc[2][1] = fmaf(q2, kv1, acc[2][1]);
      acc[2][2] = fmaf(q2, kv2, acc[2][2]); acc[2][3] = fmaf(q2, kv3, acc[2][3]);
      acc[3][0] = fmaf(q3, kv0, acc[3][0]); acc[3][1] = fmaf(q3, kv1, acc[3][1]);
      acc[3][2] = fmaf(q3, kv2, acc[3][2]); acc[3][3] = fmaf(q3, kv3, acc[3][3]);
    }
    float pr[4][4];
    softmax4(acc, v3, pr);
#pragma unroll
    for (int i = 0; i < 4; i++)
      weights_add(awn, t0 + i, lane, v3, pr[i]);
    pv_store4(vg, pr, t0, 4, n, h, lane, A2);
  }
}

// ---------------- launch ----------------
extern "C" void kernel_launch(void* const* d_in, const int* in_sizes, int n_in,
                              void* d_out, int out_size, void* d_ws, size_t ws_size,
                              hipStream_t stream)
{
  const float* query = (const float*)d_in[0];
  const float* key   = (const float*)d_in[1];
  const float* value = (const float*)d_in[2];
  const float* w_in  = (const float*)d_in[3];
  const float* b_in  = (const float*)d_in[4];
  const float* w_out = (const float*)d_in[5];
  const float* b_out = (const float*)d_in[6];

  float* out    = (float*)d_out;                       // (257,128,768)
  float* attn_w = out + (size_t)LTc * Nc * Ec;         // (128,257,197)

  // ---- workspace layout (bytes) ----
  constexpr size_t SZ_HEADF = (size_t)Bc * Lc * HDc * 4;   // 77,463,552 per fp32 head buf
  constexpr size_t OFF_CEN  = 3 * SZ_HEADF;
  constexpr size_t OFF_CN   = OFF_CEN + (size_t)Bc * Lc * 4;
  constexpr size_t R0       = OFF_CN + 8192;               // reusable region start
  constexpr size_t SZ_XB    = (size_t)25216 * 1536 * 2;    // 77,463,552 per bf16 input
  constexpr size_t SZ_A2    = (size_t)LTc * Nc * 1536 * 2; // 101,056,512
  constexpr size_t SZ_WB    = (size_t)2304 * 1536 * 2;     // 7,077,888
  constexpr size_t SZ_WOB   = (size_t)768 * 1536 * 2;      // 2,359,296
  constexpr size_t FULL_NEED = R0 + 3 * SZ_XB + SZ_WB + SZ_WOB;   // ~475.4 MB

  uint8_t* w8 = (uint8_t*)d_ws;
  float* q_ws   = (float*)w8;
  float* k_ws   = (float*)(w8 + SZ_HEADF);
  float* v_ws   = (float*)(w8 + 2 * SZ_HEADF);
  float* center = (float*)(w8 + OFF_CEN);
  float* cnorm  = (float*)(w8 + OFF_CN);
  unsigned short* A2b = (unsigned short*)(w8 + R0);        // lives during attn..gemm2

  const bool full = ws_size >= FULL_NEED;
  unsigned short* wb  = (unsigned short*)(w8 + (full ? (R0 + 3 * SZ_XB) : (R0 + SZ_XB)));
  unsigned short* wob = (unsigned short*)(w8 + (full ? (R0 + 3 * SZ_XB + SZ_WB) : (R0 + SZ_A2)));

  (void)in_sizes; (void)n_in; (void)out_size;

  // weight conversions (tiny)
  convert_hilo<<<(2304 * 192 + 255) / 256, 256, 0, stream>>>(w_in, wb, 2304);
  convert_hilo<<<(768 * 192 + 255) / 256, 256, 0, stream>>>(w_out, wob, 768);

  const int xblk = (25216 * 192 + 255) / 256;
  if (full) {
    unsigned short* xb0 = (unsigned short*)(w8 + R0);
    unsigned short* xb1 = xb0 + SZ_XB / 2;
    unsigned short* xb2 = xb1 + SZ_XB / 2;
    convert_hilo<<<xblk, 256, 0, stream>>>(query, xb0, 25216);
    convert_hilo<<<xblk, 256, 0, stream>>>(key,   xb1, 25216);
    convert_hilo<<<xblk, 256, 0, stream>>>(value, xb2, 25216);
    gemm_mfma<0><<<dim3(197, 18), 256, 0, stream>>>(xb0, xb1, xb2, wb, b_in, 0,
                                                    q_ws, k_ws, v_ws);
  } else {
    unsigned short* buf = (unsigned short*)(w8 + R0);
    const float* xs[3] = {query, key, value};
    for (int wh = 0; wh < 3; wh++) {
      convert_hilo<<<xblk, 256, 0, stream>>>(xs[wh], buf, 25216);
      gemm_mfma<0><<<dim3(197, 6), 256, 0, stream>>>(buf, buf, buf, wb, b_in, 6 * wh,
                                                     q_ws, k_ws, v_ws);
    }
  }

  center_kernel<<<dim3(1536), 256, 0, stream>>>(q_ws, k_ws, center, cnorm);

  // attn_weights accumulated atomically -> zero it (d_out is poisoned 0xAA)
  hipMemsetAsync(attn_w, 0, (size_t)Nc * LTc * Lc * sizeof(float), stream);

  attn_kernel<<<dim3(1536), 512, 0, stream>>>(q_ws, k_ws, v_ws, center, cnorm,
                                              A2b, attn_w);

  gemm_mfma<1><<<dim3(257, 6), 256, 0, stream>>>(A2b, nullptr, nullptr, wob, b_out, 0,
                                                 out, nullptr, nullptr);
}

// Round 2
// 1427.891 us; speedup vs baseline: 1.3224x; 1.1003x over previous
//
#include <hip/hip_runtime.h>
#include <stdint.h>

// ---------------- problem constants ----------------
constexpr int Lc  = 197;
constexpr int Nc  = 128;
constexpr int Ec  = 768;
constexpr int HDc = 64;
constexpr int Bc  = Nc * 12;        // 1536 batch*heads
constexpr int LTc = Lc + 60;        // 257 output rows
constexpr float EPSc = 1e-12f;

// ---------------- threefry2x32 (JAX-exact, partitionable variant) ----------------
struct U2 { uint32_t x, y; };

__device__ __forceinline__ U2 tf2x32(uint32_t k0, uint32_t k1, uint32_t x0, uint32_t x1) {
  uint32_t k2 = k0 ^ k1 ^ 0x1BD11BDAu;
  x0 += k0; x1 += k1;
#define TFR(r) { x0 += x1; x1 = (x1 << (r)) | (x1 >> (32 - (r))); x1 ^= x0; }
  TFR(13) TFR(15) TFR(26) TFR(6)
  x0 += k1; x1 += k2 + 1u;
  TFR(17) TFR(29) TFR(16) TFR(24)
  x0 += k2; x1 += k0 + 2u;
  TFR(13) TFR(15) TFR(26) TFR(6)
  x0 += k0; x1 += k1 + 3u;
  TFR(17) TFR(29) TFR(16) TFR(24)
  x0 += k1; x1 += k2 + 4u;
  TFR(13) TFR(15) TFR(26) TFR(6)
  x0 += k2; x1 += k0 + 5u;
#undef TFR
  return {x0, x1};
}

__device__ __forceinline__ float u01f(uint32_t bits) {
  return __uint_as_float((bits >> 9) | 0x3f800000u) - 1.0f;
}

__device__ __forceinline__ uint32_t rbits(uint32_t ka, uint32_t kb, uint32_t idx) {
  U2 r = tf2x32(ka, kb, 0u, idx);
  return r.x ^ r.y;
}

__device__ __forceinline__ void split_keys(uint32_t& k1a, uint32_t& k1b, uint32_t& k2a, uint32_t& k2b) {
  U2 t0 = tf2x32(0u, 1234u, 0u, 0u); k1a = t0.x; k1b = t0.y;
  U2 t1 = tf2x32(0u, 1234u, 0u, 1u); k2a = t1.x; k2b = t1.y;
}

// wave-uniform lane broadcast: VALU readlane (no LDS pipe, no lgkm wait)
__device__ __forceinline__ float rdlane(float v, int l) {
  return __int_as_float(__builtin_amdgcn_readlane(__float_as_int(v), l));
}

// ---------------- fp32 -> bf16 hi/lo split (trunc hi + exact residual) ----------------
__device__ __forceinline__ void f2hilo(float f, unsigned short& h, unsigned short& l) {
  uint32_t u = __float_as_uint(f);
  h = (unsigned short)(u >> 16);
  float lof = f - __uint_as_float(u & 0xffff0000u);
  l = (unsigned short)(__float_as_uint(lof) >> 16);
}

__device__ __forceinline__ unsigned short bf16rne(float f) {
  uint32_t u = __float_as_uint(f);
  u += 0x7fffu + ((u >> 16) & 1u);
  return (unsigned short)(u >> 16);
}

// src: rows x 768 fp32, dst: rows x 1536 bf16 (cols 0..767 = hi, 768..1535 = lo)
__global__ __launch_bounds__(256) void convert_hilo(const float* __restrict__ src,
                                                    unsigned short* __restrict__ dst,
                                                    int rows)
{
  int idx = blockIdx.x * 256 + threadIdx.x;   // one float4 per thread
  int total = rows * 192;
  if (idx >= total) return;
  int m = idx / 192, c = (idx % 192) * 4;
  float4 f = *(const float4*)(src + (size_t)m * 768 + c);
  ushort4 hv, lv;
  f2hilo(f.x, hv.x, lv.x);
  f2hilo(f.y, hv.y, lv.y);
  f2hilo(f.z, hv.z, lv.z);
  f2hilo(f.w, hv.w, lv.w);
  *(ushort4*)(dst + (size_t)m * 1536 + c) = hv;
  *(ushort4*)(dst + (size_t)m * 1536 + 768 + c) = lv;
}

// ---------------- MFMA bf16 GEMM: C = A(bf16 hi|lo, MxK=1536) @ Wb^T + bias ----------------
typedef __attribute__((ext_vector_type(8))) short bfrag_t;
typedef __attribute__((ext_vector_type(4))) float accfrag_t;

template <int MODE>
__global__ __launch_bounds__(256) void gemm_mfma(
    const unsigned short* __restrict__ A0, const unsigned short* __restrict__ A1,
    const unsigned short* __restrict__ A2in, const unsigned short* __restrict__ Wb,
    const float* __restrict__ bias, int cb,
    float* __restrict__ O0, float* __restrict__ O1, float* __restrict__ O2)
{
  __shared__ unsigned short As[128 * 40];   // stride 40 bf16 = 80 B -> 2-way max on b128 frag reads
  __shared__ unsigned short Bs[128 * 40];
  const int bm = blockIdx.x;
  const int bn = cb + blockIdx.y;
  const int tid = threadIdx.x;
  const int lane = tid & 63, wv = tid >> 6;
  const int wm = (wv & 1) * 64, wn = (wv >> 1) * 64;
  const int q4 = lane >> 4, l16 = lane & 15;

  const unsigned short* A;
  int which = 0;
  if (MODE == 0) { which = bn / 6; A = which == 0 ? A0 : (which == 1 ? A1 : A2in); }
  else A = A0;

  const int sr = tid >> 2;           // staging row within 64-row half
  const int sc = (tid & 3) * 8;      // staging col (8 bf16 = 16 B)

  accfrag_t acc[4][4];
#pragma unroll
  for (int i = 0; i < 4; i++)
#pragma unroll
    for (int j = 0; j < 4; j++)
#pragma unroll
      for (int r = 0; r < 4; r++) acc[i][j][r] = 0.0f;

  for (int kt = 0; kt < 48; kt++) {
    const int k0 = kt * 32;
    __syncthreads();
#pragma unroll
    for (int p = 0; p < 2; p++) {
      int r = p * 64 + sr;
      uint4 av = *(const uint4*)(A  + (size_t)(bm * 128 + r) * 1536 + k0 + sc);
      *(uint4*)&As[r * 40 + sc] = av;
      uint4 bv = *(const uint4*)(Wb + (size_t)(bn * 128 + r) * 1536 + k0 + sc);
      *(uint4*)&Bs[r * 40 + sc] = bv;
    }
    __syncthreads();
    bfrag_t af[4], bf[4];
#pragma unroll
    for (int i = 0; i < 4; i++) {
      af[i] = *(const bfrag_t*)&As[(wm + i * 16 + l16) * 40 + q4 * 8];
      bf[i] = *(const bfrag_t*)&Bs[(wn + i * 16 + l16) * 40 + q4 * 8];
    }
#pragma unroll
    for (int i = 0; i < 4; i++)
#pragma unroll
      for (int j = 0; j < 4; j++)
        acc[i][j] = __builtin_amdgcn_mfma_f32_16x16x32_bf16(af[i], bf[j], acc[i][j], 0, 0, 0);
  }

  float bv4[4];
#pragma unroll
  for (int j = 0; j < 4; j++) bv4[j] = bias[bn * 128 + wn + j * 16 + l16];

  if (MODE == 0) {
    const float scale = (which == 0) ? 0.125f : 1.0f;
    float* O = which == 0 ? O0 : (which == 1 ? O1 : O2);
#pragma unroll
    for (int i = 0; i < 4; i++) {
#pragma unroll
      for (int r = 0; r < 4; r++) {
        int m = bm * 128 + wm + i * 16 + q4 * 4 + r;   // m = l*128 + n
        int l = m >> 7, nb = m & 127;
#pragma unroll
        for (int j = 0; j < 4; j++) {
          int ng = bn * 128 + wn + j * 16 + l16;
          int nc = ng - which * 768;
          int h = nc >> 6, d = nc & 63;
          O[(((size_t)(nb * 12 + h)) * 197 + l) * 64 + d] = (acc[i][j][r] + bv4[j]) * scale;
        }
      }
    }
  } else {
#pragma unroll
    for (int i = 0; i < 4; i++) {
#pragma unroll
      for (int r = 0; r < 4; r++) {
        int m = bm * 128 + wm + i * 16 + q4 * 4 + r;
#pragma unroll
        for (int j = 0; j < 4; j++) {
          int ng = bn * 128 + wn + j * 16 + l16;
          O0[(size_t)m * 768 + ng] = acc[i][j][r] + bv4[j];
        }
      }
    }
  }
}

// ---------------- K2: center row (= S[b,0,:]) and its norm ----------------
__global__ __launch_bounds__(256) void center_kernel(
    const float* __restrict__ q_ws, const float* __restrict__ k_ws,
    float* __restrict__ center, float* __restrict__ cnorm)
{
  const int b = blockIdx.x;
  const int lane = threadIdx.x & 63, w = threadIdx.x >> 6;
  __shared__ float ssh[4];
  const float q0 = q_ws[(size_t)b * (197 * 64) + lane];
  float ss = 0.0f;
  for (int s = w; s < 197; s += 4) {
    float val = q0 * k_ws[((size_t)b * 197 + s) * 64 + lane];
#pragma unroll
    for (int off = 32; off >= 1; off >>= 1) val += __shfl_xor(val, off, 64);
    if (lane == 0) center[(size_t)b * 197 + s] = val;
    ss += val * val;
  }
  if (lane == 0) ssh[w] = ss;
  __syncthreads();
  if (threadIdx.x == 0) cnorm[b] = sqrtf(ssh[0] + ssh[1] + ssh[2] + ssh[3]);
}

// ---------------- K3 helpers ----------------
// batched 4-row softmax: the 4 rows' reduction chains interleave (latency /4)
__device__ __forceinline__ void softmax4(float x[4][4], bool v3, float p[4][4])
{
  float m[4], s[4];
#pragma unroll
  for (int i = 0; i < 4; i++) {
    m[i] = fmaxf(fmaxf(x[i][0], x[i][1]), x[i][2]);
    if (v3) m[i] = fmaxf(m[i], x[i][3]);
  }
#pragma unroll
  for (int off = 32; off >= 1; off >>= 1) {
#pragma unroll
    for (int i = 0; i < 4; i++) m[i] = fmaxf(m[i], __shfl_xor(m[i], off, 64));
  }
#pragma unroll
  for (int i = 0; i < 4; i++) {
    float e0 = __expf(x[i][0] - m[i]);
    float e1 = __expf(x[i][1] - m[i]);
    float e2 = __expf(x[i][2] - m[i]);
    float e3 = v3 ? __expf(x[i][3] - m[i]) : 0.0f;
    p[i][0] = e0; p[i][1] = e1; p[i][2] = e2; p[i][3] = e3;
    s[i] = e0 + e1 + e2 + e3;
  }
#pragma unroll
  for (int off = 32; off >= 1; off >>= 1) {
#pragma unroll
    for (int i = 0; i < 4; i++) s[i] += __shfl_xor(s[i], off, 64);
  }
#pragma unroll
  for (int i = 0; i < 4; i++) {
    float rs = 1.0f / s[i];
    p[i][0] *= rs; p[i][1] *= rs; p[i][2] *= rs; p[i][3] *= rs;
  }
}

__device__ __forceinline__ void weights_add(float* __restrict__ awn, int t, int lane,
                                            bool v3, const float* p)
{
  float* a = awn + (size_t)t * 197;
  const float c = 1.0f / 12.0f;
  atomicAdd(a + lane, p[0] * c);
  atomicAdd(a + lane + 64, p[1] * c);
  atomicAdd(a + lane + 128, p[2] * c);
  if (v3) atomicAdd(a + lane + 192, p[3] * c);
}

// ---------------- K3: fused scores + RNG rows + softmax + MFMA PV + weights ----------------
// Chunked: 9 chunks of 32 rows. Per chunk: 8 waves x one 4-row scalar score group
// (RNG/center/QK) -> P_lds bf16 -> barrier -> 8 waves x one 16x16 PV MFMA tile
// (2 t-tiles x 4 d-tiles) reading V^T hi/lo bf16 from LDS -> barrier.
// LDS: kT 51456 + Vth/Vtl 59392 + Pl 14848 + cen/uu 1600 = 127296 B -> 1 block/CU.
// Strides 232 bf16 (=464 B = 116 dw, 116%32=20 -> 2-way max aliasing, 16B-aligned rows).
__global__ __launch_bounds__(512, 2) void attn_kernel(
    const float* __restrict__ q_ws, const float* __restrict__ k_ws, const float* __restrict__ v_ws,
    const float* __restrict__ center, const float* __restrict__ cnorm,
    unsigned short* __restrict__ A2, float* __restrict__ attn_w)
{
  __shared__ float kT[64][201];                       // staging banks (9d+s)%32 -> 2-way max
  __shared__ __align__(16) unsigned short Vth[64 * 232];   // V^T hi, [d][s]
  __shared__ __align__(16) unsigned short Vtl[64 * 232];   // V^T lo
  __shared__ __align__(16) unsigned short Pl[32 * 232];    // P chunk, [slot][s] bf16
  __shared__ float cen[200];
  __shared__ float uu[200];

  const int b = blockIdx.x;
  const int n = b / 12, h = b % 12;
  const int tid = threadIdx.x;
  const int lane = tid & 63, w = tid >> 6;
  const int q4 = lane >> 4, l16 = lane & 15;
  const bool v3 = lane < 5;

  const float* kg = k_ws + (size_t)b * (197 * 64);
  const float* vg = v_ws + (size_t)b * (197 * 64);
  const float* qg = q_ws + (size_t)b * (197 * 64);

  // zero pad columns s=197..231 (disjoint from fills below -> no extra barrier)
  for (int idx = tid; idx < 64 * 35; idx += 512) {
    int d = idx / 35, s = 197 + idx % 35;
    Vth[d * 232 + s] = 0;
    Vtl[d * 232 + s] = 0;
  }
  for (int idx = tid; idx < 32 * 35; idx += 512) {
    int r = idx / 35, s = 197 + idx % 35;
    Pl[r * 232 + s] = 0;
  }

  // stage kT (fp32, transposed) and V^T (bf16 hi/lo, transposed)
  for (int idx = tid; idx < 197 * 64; idx += 512) {
    int s = idx >> 6, d = idx & 63;
    kT[d][s] = kg[idx];
    unsigned short vh, vl;
    f2hilo(vg[idx], vh, vl);
    Vth[d * 232 + s] = vh;
    Vtl[d * 232 + s] = vl;
  }
  {
    float inv = 1.0f / fmaxf(cnorm[b], EPSc);
    for (int s = tid; s < 197; s += 512) {
      float c = center[(size_t)b * 197 + s];
      cen[s] = c;
      uu[s] = c * inv;
    }
  }
  __syncthreads();

  // per-lane-constant unit-center components
  const float us0 = uu[lane], us1 = uu[lane + 64], us2 = uu[lane + 128];
  const float us3 = v3 ? uu[lane + 192] : 0.0f;

  const float cnb = cnorm[b];
  uint32_t k1a, k1b, k2a, k2b;
  split_keys(k1a, k1b, k2a, k2b);
  float* awn = attn_w + (size_t)n * (LTc * 197);

  for (int c = 0; c < 9; c++) {
    const int t0 = c * 32 + w * 4;                  // c==8: only w==0 valid (t0=256)
    const bool sact = (c < 8) || (w == 0);

    if (sact) {
      float x[4][4];
      // batched scalar QK for any row >= 61 (invalid rows overwritten / discarded)
      if (t0 + 3 >= 61) {
        float qr[4];
#pragma unroll
        for (int i = 0; i < 4; i++) {
          int l = t0 + i - 60;
          l = l < 0 ? 0 : (l > 196 ? 196 : l);
          qr[i] = qg[(size_t)l * 64 + lane];
        }
#pragma unroll
        for (int i = 0; i < 4; i++)
#pragma unroll
          for (int j = 0; j < 4; j++) x[i][j] = 0.0f;
#pragma unroll 4
        for (int d = 0; d < 64; d++) {
          float q0 = rdlane(qr[0], d), q1 = rdlane(qr[1], d);
          float q2 = rdlane(qr[2], d), q3 = rdlane(qr[3], d);
          float kv0 = kT[d][lane], kv1 = kT[d][lane + 64], kv2 = kT[d][lane + 128];
          float kv3 = v3 ? kT[d][lane + 192] : 0.0f;
          x[0][0] = fmaf(q0, kv0, x[0][0]); x[0][1] = fmaf(q0, kv1, x[0][1]);
          x[0][2] = fmaf(q0, kv2, x[0][2]); x[0][3] = fmaf(q0, kv3, x[0][3]);
          x[1][0] = fmaf(q1, kv0, x[1][0]); x[1][1] = fmaf(q1, kv1, x[1][1]);
          x[1][2] = fmaf(q1, kv2, x[1][2]); x[1][3] = fmaf(q1, kv3, x[1][3]);
          x[2][0] = fmaf(q2, kv0, x[2][0]); x[2][1] = fmaf(q2, kv1, x[2][1]);
          x[2][2] = fmaf(q2, kv2, x[2][2]); x[2][3] = fmaf(q2, kv3, x[2][3]);
          x[3][0] = fmaf(q3, kv0, x[3][0]); x[3][1] = fmaf(q3, kv1, x[3][1]);
          x[3][2] = fmaf(q3, kv2, x[3][2]); x[3][3] = fmaf(q3, kv3, x[3][3]);
        }
      }
      // center / RNG rows (t < 61) overwrite
#pragma unroll
      for (int i = 0; i < 4; i++) {
        const int t = t0 + i;
        if (t >= 61) continue;
        if (t == 0) {
          x[0][0] = cen[lane]; x[0][1] = cen[lane + 64]; x[0][2] = cen[lane + 128];
          x[0][3] = v3 ? cen[lane + 192] : 0.0f;
        } else {
          const int ns = t - 1;
          const uint32_t base = ((uint32_t)ns * 1536u + (uint32_t)b) * 197u;
          float r0 = u01f(rbits(k1a, k1b, base + lane))       * 2.0f - 1.0f;
          float r1 = u01f(rbits(k1a, k1b, base + lane + 64))  * 2.0f - 1.0f;
          float r2 = u01f(rbits(k1a, k1b, base + lane + 128)) * 2.0f - 1.0f;
          float r3 = v3 ? (u01f(rbits(k1a, k1b, base + lane + 192)) * 2.0f - 1.0f) : 0.0f;
          float pa = r0 * us0 + r1 * us1 + r2 * us2 + r3 * us3;
#pragma unroll
          for (int off = 32; off >= 1; off >>= 1) pa += __shfl_xor(pa, off, 64);
          float rp0 = r0 - pa * us0, rp1 = r1 - pa * us1;
          float rp2 = r2 - pa * us2, rp3 = r3 - pa * us3;
          float sq2 = rp0 * rp0 + rp1 * rp1 + rp2 * rp2 + (v3 ? rp3 * rp3 : 0.0f);
#pragma unroll
          for (int off = 32; off >= 1; off >>= 1) sq2 += __shfl_xor(sq2, off, 64);
          float invn = 1.0f / fmaxf(sqrtf(sq2), EPSc);
          float cv = u01f(rbits(k2a, k2b, (uint32_t)ns)) * 0.2f + 0.7f;
          float sv = sqrtf(1.0f - cv * cv);
          float f = sv * invn;
          x[i][0] = cnb * (cv * us0 + f * rp0);
          x[i][1] = cnb * (cv * us1 + f * rp1);
          x[i][2] = cnb * (cv * us2 + f * rp2);
          x[i][3] = cnb * (cv * us3 + f * rp3);
        }
      }
      float pr[4][4];
      softmax4(x, v3, pr);
#pragma unroll
      for (int i = 0; i < 4; i++)
        if (c < 8 || i == 0) weights_add(awn, t0 + i, lane, v3, pr[i]);
      // P -> LDS (bf16 RNE); slot = w*4+i (c==8: w==0 -> slot=i)
#pragma unroll
      for (int i = 0; i < 4; i++) {
        unsigned short* pRow = Pl + (w * 4 + i) * 232;
        pRow[lane]       = bf16rne(pr[i][0]);
        pRow[lane + 64]  = bf16rne(pr[i][1]);
        pRow[lane + 128] = bf16rne(pr[i][2]);
        if (v3) pRow[lane + 192] = bf16rne(pr[i][3]);
      }
    }
    __syncthreads();

    // PV MFMA: wave w -> t-tile (w>>2), d-tile (w&3); c==8: waves 0..3, t-tile 0
    const bool pvact = (c < 8) || (w < 4);
    if (pvact) {
      const int tt = (c < 8) ? (w >> 2) : 0;
      const int dj = (c < 8) ? (w & 3) : w;
      accfrag_t acc = {0.0f, 0.0f, 0.0f, 0.0f};
      const unsigned short* pA = Pl  + (tt * 16 + l16) * 232 + q4 * 8;
      const unsigned short* pH = Vth + (dj * 16 + l16) * 232 + q4 * 8;
      const unsigned short* pL = Vtl + (dj * 16 + l16) * 232 + q4 * 8;
#pragma unroll
      for (int ks = 0; ks < 7; ks++) {
        bfrag_t af = *(const bfrag_t*)(pA + ks * 32);
        bfrag_t bh = *(const bfrag_t*)(pH + ks * 32);
        bfrag_t bl = *(const bfrag_t*)(pL + ks * 32);
        acc = __builtin_amdgcn_mfma_f32_16x16x32_bf16(af, bh, acc, 0, 0, 0);
        acc = __builtin_amdgcn_mfma_f32_16x16x32_bf16(af, bl, acc, 0, 0, 0);
      }
      const int tbase = c * 32 + tt * 16 + q4 * 4;
      const int d = dj * 16 + l16;
#pragma unroll
      for (int r = 0; r < 4; r++) {
        const int t = tbase + r;
        if (t <= 256) {
          unsigned short hb, lb;
          f2hilo(acc[r], hb, lb);
          size_t base = ((size_t)t * 128 + n) * 1536 + h * 64 + d;
          A2[base] = hb;
          A2[base + 768] = lb;
        }
      }
    }
    __syncthreads();
  }
}

// ---------------- launch ----------------
extern "C" void kernel_launch(void* const* d_in, const int* in_sizes, int n_in,
                              void* d_out, int out_size, void* d_ws, size_t ws_size,
                              hipStream_t stream)
{
  const float* query = (const float*)d_in[0];
  const float* key   = (const float*)d_in[1];
  const float* value = (const float*)d_in[2];
  const float* w_in  = (const float*)d_in[3];
  const float* b_in  = (const float*)d_in[4];
  const float* w_out = (const float*)d_in[5];
  const float* b_out = (const float*)d_in[6];

  float* out    = (float*)d_out;                       // (257,128,768)
  float* attn_w = out + (size_t)LTc * Nc * Ec;         // (128,257,197)

  // ---- workspace layout (bytes) ----
  constexpr size_t SZ_HEADF = (size_t)Bc * Lc * HDc * 4;   // 77,463,552 per fp32 head buf
  constexpr size_t OFF_CEN  = 3 * SZ_HEADF;
  constexpr size_t OFF_CN   = OFF_CEN + (size_t)Bc * Lc * 4;
  constexpr size_t R0       = OFF_CN + 8192;               // reusable region start
  constexpr size_t SZ_XB    = (size_t)25216 * 1536 * 2;    // 77,463,552 per bf16 input
  constexpr size_t SZ_A2    = (size_t)LTc * Nc * 1536 * 2; // 101,056,512
  constexpr size_t SZ_WB    = (size_t)2304 * 1536 * 2;     // 7,077,888
  constexpr size_t SZ_WOB   = (size_t)768 * 1536 * 2;      // 2,359,296
  constexpr size_t FULL_NEED = R0 + 3 * SZ_XB + SZ_WB + SZ_WOB;   // ~475.4 MB

  uint8_t* w8 = (uint8_t*)d_ws;
  float* q_ws   = (float*)w8;
  float* k_ws   = (float*)(w8 + SZ_HEADF);
  float* v_ws   = (float*)(w8 + 2 * SZ_HEADF);
  float* center = (float*)(w8 + OFF_CEN);
  float* cnorm  = (float*)(w8 + OFF_CN);
  unsigned short* A2b = (unsigned short*)(w8 + R0);        // lives during attn..gemm2

  const bool full = ws_size >= FULL_NEED;
  unsigned short* wb  = (unsigned short*)(w8 + (full ? (R0 + 3 * SZ_XB) : (R0 + SZ_XB)));
  unsigned short* wob = (unsigned short*)(w8 + (full ? (R0 + 3 * SZ_XB + SZ_WB) : (R0 + SZ_A2)));

  (void)in_sizes; (void)n_in; (void)out_size;

  // weight conversions (tiny)
  convert_hilo<<<(2304 * 192 + 255) / 256, 256, 0, stream>>>(w_in, wb, 2304);
  convert_hilo<<<(768 * 192 + 255) / 256, 256, 0, stream>>>(w_out, wob, 768);

  const int xblk = (25216 * 192 + 255) / 256;
  if (full) {
    unsigned short* xb0 = (unsigned short*)(w8 + R0);
    unsigned short* xb1 = xb0 + SZ_XB / 2;
    unsigned short* xb2 = xb1 + SZ_XB / 2;
    convert_hilo<<<xblk, 256, 0, stream>>>(query, xb0, 25216);
    convert_hilo<<<xblk, 256, 0, stream>>>(key,   xb1, 25216);
    convert_hilo<<<xblk, 256, 0, stream>>>(value, xb2, 25216);
    gemm_mfma<0><<<dim3(197, 18), 256, 0, stream>>>(xb0, xb1, xb2, wb, b_in, 0,
                                                    q_ws, k_ws, v_ws);
  } else {
    unsigned short* buf = (unsigned short*)(w8 + R0);
    const float* xs[3] = {query, key, value};
    for (int wh = 0; wh < 3; wh++) {
      convert_hilo<<<xblk, 256, 0, stream>>>(xs[wh], buf, 25216);
      gemm_mfma<0><<<dim3(197, 6), 256, 0, stream>>>(buf, buf, buf, wb, b_in, 6 * wh,
                                                     q_ws, k_ws, v_ws);
    }
  }

  center_kernel<<<dim3(1536), 256, 0, stream>>>(q_ws, k_ws, center, cnorm);

  // attn_weights accumulated atomically -> zero it (d_out is poisoned 0xAA)
  hipMemsetAsync(attn_w, 0, (size_t)Nc * LTc * Lc * sizeof(float), stream);

  attn_kernel<<<dim3(1536), 512, 0, stream>>>(q_ws, k_ws, v_ws, center, cnorm,
                                              A2b, attn_w);

  gemm_mfma<1><<<dim3(257, 6), 256, 0, stream>>>(A2b, nullptr, nullptr, wob, b_out, 0,
                                                 out, nullptr, nullptr);
}

// Round 3
// 1315.297 us; speedup vs baseline: 1.4356x; 1.0856x over previous
//
#include <hip/hip_runtime.h>
#include <stdint.h>

// ---------------- problem constants ----------------
constexpr int Lc  = 197;
constexpr int Nc  = 128;
constexpr int Ec  = 768;
constexpr int HDc = 64;
constexpr int Bc  = Nc * 12;        // 1536 batch*heads
constexpr int LTc = Lc + 60;        // 257 output rows
constexpr float EPSc = 1e-12f;

// ---------------- threefry2x32 (JAX-exact, partitionable variant) ----------------
struct U2 { uint32_t x, y; };

__device__ __forceinline__ U2 tf2x32(uint32_t k0, uint32_t k1, uint32_t x0, uint32_t x1) {
  uint32_t k2 = k0 ^ k1 ^ 0x1BD11BDAu;
  x0 += k0; x1 += k1;
#define TFR(r) { x0 += x1; x1 = (x1 << (r)) | (x1 >> (32 - (r))); x1 ^= x0; }
  TFR(13) TFR(15) TFR(26) TFR(6)
  x0 += k1; x1 += k2 + 1u;
  TFR(17) TFR(29) TFR(16) TFR(24)
  x0 += k2; x1 += k0 + 2u;
  TFR(13) TFR(15) TFR(26) TFR(6)
  x0 += k0; x1 += k1 + 3u;
  TFR(17) TFR(29) TFR(16) TFR(24)
  x0 += k1; x1 += k2 + 4u;
  TFR(13) TFR(15) TFR(26) TFR(6)
  x0 += k2; x1 += k0 + 5u;
#undef TFR
  return {x0, x1};
}

__device__ __forceinline__ float u01f(uint32_t bits) {
  return __uint_as_float((bits >> 9) | 0x3f800000u) - 1.0f;
}

__device__ __forceinline__ uint32_t rbits(uint32_t ka, uint32_t kb, uint32_t idx) {
  U2 r = tf2x32(ka, kb, 0u, idx);
  return r.x ^ r.y;
}

__device__ __forceinline__ void split_keys(uint32_t& k1a, uint32_t& k1b, uint32_t& k2a, uint32_t& k2b) {
  U2 t0 = tf2x32(0u, 1234u, 0u, 0u); k1a = t0.x; k1b = t0.y;
  U2 t1 = tf2x32(0u, 1234u, 0u, 1u); k2a = t1.x; k2b = t1.y;
}

// wave-uniform lane broadcast: VALU readlane (no LDS pipe, no lgkm wait)
__device__ __forceinline__ float rdlane(float v, int l) {
  return __int_as_float(__builtin_amdgcn_readlane(__float_as_int(v), l));
}

// async global->LDS, 16B per lane (lds dest = wave-uniform base + lane*16)
__device__ __forceinline__ void gl_lds16(const unsigned short* g, unsigned short* l) {
  __builtin_amdgcn_global_load_lds((const __attribute__((address_space(1))) void*)g,
                                   (__attribute__((address_space(3))) void*)l, 16, 0, 0);
}

// ---------------- fp32 -> bf16 hi/lo split (trunc hi + exact residual) ----------------
__device__ __forceinline__ void f2hilo(float f, unsigned short& h, unsigned short& l) {
  uint32_t u = __float_as_uint(f);
  h = (unsigned short)(u >> 16);
  float lof = f - __uint_as_float(u & 0xffff0000u);
  l = (unsigned short)(__float_as_uint(lof) >> 16);
}

__device__ __forceinline__ unsigned short bf16rne(float f) {
  uint32_t u = __float_as_uint(f);
  u += 0x7fffu + ((u >> 16) & 1u);
  return (unsigned short)(u >> 16);
}

// src: rows x 768 fp32, dst: rows x 1536 bf16 (cols 0..767 = hi, 768..1535 = lo)
__global__ __launch_bounds__(256) void convert_hilo(const float* __restrict__ src,
                                                    unsigned short* __restrict__ dst,
                                                    int rows)
{
  int idx = blockIdx.x * 256 + threadIdx.x;   // one float4 per thread
  int total = rows * 192;
  if (idx >= total) return;
  int m = idx / 192, c = (idx % 192) * 4;
  float4 f = *(const float4*)(src + (size_t)m * 768 + c);
  ushort4 hv, lv;
  f2hilo(f.x, hv.x, lv.x);
  f2hilo(f.y, hv.y, lv.y);
  f2hilo(f.z, hv.z, lv.z);
  f2hilo(f.w, hv.w, lv.w);
  *(ushort4*)(dst + (size_t)m * 1536 + c) = hv;
  *(ushort4*)(dst + (size_t)m * 1536 + 768 + c) = lv;
}

// ---------------- MFMA bf16 GEMM: C = A(bf16 hi|lo, MxK=1536) @ Wb^T + bias ----------------
// m97-style staging: global_load_lds dwordx4, linear LDS [128][32] bf16 per tile.
typedef __attribute__((ext_vector_type(8))) short bfrag_t;
typedef __attribute__((ext_vector_type(4))) float accfrag_t;

template <int MODE>
__global__ __launch_bounds__(256) void gemm_mfma(
    const unsigned short* __restrict__ A0, const unsigned short* __restrict__ A1,
    const unsigned short* __restrict__ A2in, const unsigned short* __restrict__ Wb,
    const float* __restrict__ bias, int cb,
    float* __restrict__ O0, float* __restrict__ O1, float* __restrict__ O2)
{
  __shared__ __align__(16) unsigned short As[128 * 32];
  __shared__ __align__(16) unsigned short Bs[128 * 32];
  const int bm = blockIdx.x;
  const int bn = cb + blockIdx.y;
  const int tid = threadIdx.x;
  const int lane = tid & 63, wv = tid >> 6;
  const int wm = (wv & 1) * 64, wn = (wv >> 1) * 64;
  const int q4 = lane >> 4, l16 = lane & 15;

  const unsigned short* A;
  int which = 0;
  if (MODE == 0) { which = bn / 6; A = which == 0 ? A0 : (which == 1 ? A1 : A2in); }
  else A = A0;

  // staging addressing: lane writes LDS bytes (wv*1024 + lane*16) [+4096 for p=1]
  // -> row = p*64 + wv*16 + (lane>>2), col8 = (lane&3)*8; global src matches.
  const int srow = wv * 16 + (lane >> 2);
  const int scol = (lane & 3) * 8;

  accfrag_t acc[4][4];
#pragma unroll
  for (int i = 0; i < 4; i++)
#pragma unroll
    for (int j = 0; j < 4; j++)
#pragma unroll
      for (int r = 0; r < 4; r++) acc[i][j][r] = 0.0f;

  for (int kt = 0; kt < 48; kt++) {
    const int k0 = kt * 32;
    __syncthreads();
    gl_lds16(A  + (size_t)(bm * 128 + srow) * 1536 + k0 + scol,      &As[wv * 512]);
    gl_lds16(Wb + (size_t)(bn * 128 + srow) * 1536 + k0 + scol,      &Bs[wv * 512]);
    gl_lds16(A  + (size_t)(bm * 128 + 64 + srow) * 1536 + k0 + scol, &As[2048 + wv * 512]);
    gl_lds16(Wb + (size_t)(bn * 128 + 64 + srow) * 1536 + k0 + scol, &Bs[2048 + wv * 512]);
    __syncthreads();
    bfrag_t af[4], bf[4];
#pragma unroll
    for (int i = 0; i < 4; i++) {
      af[i] = *(const bfrag_t*)&As[(wm + i * 16 + l16) * 32 + q4 * 8];
      bf[i] = *(const bfrag_t*)&Bs[(wn + i * 16 + l16) * 32 + q4 * 8];
    }
#pragma unroll
    for (int i = 0; i < 4; i++)
#pragma unroll
      for (int j = 0; j < 4; j++)
        acc[i][j] = __builtin_amdgcn_mfma_f32_16x16x32_bf16(af[i], bf[j], acc[i][j], 0, 0, 0);
  }

  float bv4[4];
#pragma unroll
  for (int j = 0; j < 4; j++) bv4[j] = bias[bn * 128 + wn + j * 16 + l16];

  if (MODE == 0) {
    const float scale = (which == 0) ? 0.125f : 1.0f;
    float* O = which == 0 ? O0 : (which == 1 ? O1 : O2);
#pragma unroll
    for (int i = 0; i < 4; i++) {
#pragma unroll
      for (int r = 0; r < 4; r++) {
        int m = bm * 128 + wm + i * 16 + q4 * 4 + r;   // m = l*128 + n
        int l = m >> 7, nb = m & 127;
#pragma unroll
        for (int j = 0; j < 4; j++) {
          int ng = bn * 128 + wn + j * 16 + l16;
          int nc = ng - which * 768;
          int h = nc >> 6, d = nc & 63;
          O[(((size_t)(nb * 12 + h)) * 197 + l) * 64 + d] = (acc[i][j][r] + bv4[j]) * scale;
        }
      }
    }
  } else {
#pragma unroll
    for (int i = 0; i < 4; i++) {
#pragma unroll
      for (int r = 0; r < 4; r++) {
        int m = bm * 128 + wm + i * 16 + q4 * 4 + r;
#pragma unroll
        for (int j = 0; j < 4; j++) {
          int ng = bn * 128 + wn + j * 16 + l16;
          O0[(size_t)m * 768 + ng] = acc[i][j][r] + bv4[j];
        }
      }
    }
  }
}

// ---------------- K2: center row (= S[b,0,:]) and its norm ----------------
__global__ __launch_bounds__(256) void center_kernel(
    const float* __restrict__ q_ws, const float* __restrict__ k_ws,
    float* __restrict__ center, float* __restrict__ cnorm)
{
  const int b = blockIdx.x;
  const int lane = threadIdx.x & 63, w = threadIdx.x >> 6;
  __shared__ float ssh[4];
  const float q0 = q_ws[(size_t)b * (197 * 64) + lane];
  float ss = 0.0f;
  for (int s = w; s < 197; s += 4) {
    float val = q0 * k_ws[((size_t)b * 197 + s) * 64 + lane];
#pragma unroll
    for (int off = 32; off >= 1; off >>= 1) val += __shfl_xor(val, off, 64);
    if (lane == 0) center[(size_t)b * 197 + s] = val;
    ss += val * val;
  }
  if (lane == 0) ssh[w] = ss;
  __syncthreads();
  if (threadIdx.x == 0) cnorm[b] = sqrtf(ssh[0] + ssh[1] + ssh[2] + ssh[3]);
}

// ---------------- K3 helpers ----------------
// batched 4-row softmax: the 4 rows' reduction chains interleave (latency /4)
__device__ __forceinline__ void softmax4(float x[4][4], bool v3, float p[4][4])
{
  float m[4], s[4];
#pragma unroll
  for (int i = 0; i < 4; i++) {
    m[i] = fmaxf(fmaxf(x[i][0], x[i][1]), x[i][2]);
    if (v3) m[i] = fmaxf(m[i], x[i][3]);
  }
#pragma unroll
  for (int off = 32; off >= 1; off >>= 1) {
#pragma unroll
    for (int i = 0; i < 4; i++) m[i] = fmaxf(m[i], __shfl_xor(m[i], off, 64));
  }
#pragma unroll
  for (int i = 0; i < 4; i++) {
    float e0 = __expf(x[i][0] - m[i]);
    float e1 = __expf(x[i][1] - m[i]);
    float e2 = __expf(x[i][2] - m[i]);
    float e3 = v3 ? __expf(x[i][3] - m[i]) : 0.0f;
    p[i][0] = e0; p[i][1] = e1; p[i][2] = e2; p[i][3] = e3;
    s[i] = e0 + e1 + e2 + e3;
  }
#pragma unroll
  for (int off = 32; off >= 1; off >>= 1) {
#pragma unroll
    for (int i = 0; i < 4; i++) s[i] += __shfl_xor(s[i], off, 64);
  }
#pragma unroll
  for (int i = 0; i < 4; i++) {
    float rs = 1.0f / s[i];
    p[i][0] *= rs; p[i][1] *= rs; p[i][2] *= rs; p[i][3] *= rs;
  }
}

__device__ __forceinline__ void weights_add(float* __restrict__ awn, int t, int lane,
                                            bool v3, const float* p)
{
  float* a = awn + (size_t)t * 197;
  const float c = 1.0f / 12.0f;
  atomicAdd(a + lane, p[0] * c);
  atomicAdd(a + lane + 64, p[1] * c);
  atomicAdd(a + lane + 128, p[2] * c);
  if (v3) atomicAdd(a + lane + 192, p[3] * c);
}

// ---------------- K3: fused scores + RNG rows + softmax + MFMA PV + weights ----------------
// 9 chunks of 32 rows, software-pipelined: phase c = { score(c) -> Pl[c&1]  ||
// PV(c-1) from Pl[(c-1)&1] } with ONE barrier per phase (Pl double-buffered).
// LDS: kT 51456 + Vth/Vtl 59392 + Pl 2x14848 + cen/uu 1600 = 142144 B -> 1 block/CU.
__global__ __launch_bounds__(512, 2) void attn_kernel(
    const float* __restrict__ q_ws, const float* __restrict__ k_ws, const float* __restrict__ v_ws,
    const float* __restrict__ center, const float* __restrict__ cnorm,
    unsigned short* __restrict__ A2, float* __restrict__ attn_w)
{
  __shared__ float kT[64][201];                       // staging banks (9d+s)%32 -> 2-way max
  __shared__ __align__(16) unsigned short Vth[64 * 232];   // V^T hi, [d][s]
  __shared__ __align__(16) unsigned short Vtl[64 * 232];   // V^T lo
  __shared__ __align__(16) unsigned short Pl[2][32 * 232]; // P chunk, [buf][slot][s] bf16
  __shared__ float cen[200];
  __shared__ float uu[200];

  const int b = blockIdx.x;
  const int n = b / 12, h = b % 12;
  const int tid = threadIdx.x;
  const int lane = tid & 63, w = tid >> 6;
  const int q4 = lane >> 4, l16 = lane & 15;
  const bool v3 = lane < 5;

  const float* kg = k_ws + (size_t)b * (197 * 64);
  const float* vg = v_ws + (size_t)b * (197 * 64);
  const float* qg = q_ws + (size_t)b * (197 * 64);

  // zero pad columns s=197..231 (disjoint from fills below -> no extra barrier)
  for (int idx = tid; idx < 64 * 35; idx += 512) {
    int d = idx / 35, s = 197 + idx % 35;
    Vth[d * 232 + s] = 0;
    Vtl[d * 232 + s] = 0;
  }
  for (int idx = tid; idx < 2 * 32 * 35; idx += 512) {
    int bb = idx / (32 * 35), r = (idx / 35) & 31, s = 197 + idx % 35;
    Pl[bb][r * 232 + s] = 0;
  }

  // stage kT (fp32, transposed) and V^T (bf16 hi/lo, transposed)
  for (int idx = tid; idx < 197 * 64; idx += 512) {
    int s = idx >> 6, d = idx & 63;
    kT[d][s] = kg[idx];
    unsigned short vh, vl;
    f2hilo(vg[idx], vh, vl);
    Vth[d * 232 + s] = vh;
    Vtl[d * 232 + s] = vl;
  }
  {
    float inv = 1.0f / fmaxf(cnorm[b], EPSc);
    for (int s = tid; s < 197; s += 512) {
      float c = center[(size_t)b * 197 + s];
      cen[s] = c;
      uu[s] = c * inv;
    }
  }
  __syncthreads();

  // per-lane-constant unit-center components
  const float us0 = uu[lane], us1 = uu[lane + 64], us2 = uu[lane + 128];
  const float us3 = v3 ? uu[lane + 192] : 0.0f;

  const float cnb = cnorm[b];
  uint32_t k1a, k1b, k2a, k2b;
  split_keys(k1a, k1b, k2a, k2b);
  float* awn = attn_w + (size_t)n * (LTc * 197);

  for (int c = 0; c <= 9; c++) {
    // ---- score phase for chunk c (c<=8) ----
    if (c <= 8) {
      const int t0 = c * 32 + w * 4;                  // c==8: only w==0 valid (t0=256)
      const bool sact = (c < 8) || (w == 0);
      if (sact) {
        float x[4][4];
        if (t0 + 3 >= 61) {
          float qr[4];
#pragma unroll
          for (int i = 0; i < 4; i++) {
            int l = t0 + i - 60;
            l = l < 0 ? 0 : (l > 196 ? 196 : l);
            qr[i] = qg[(size_t)l * 64 + lane];
          }
#pragma unroll
          for (int i = 0; i < 4; i++)
#pragma unroll
            for (int j = 0; j < 4; j++) x[i][j] = 0.0f;
#pragma unroll 4
          for (int d = 0; d < 64; d++) {
            float q0 = rdlane(qr[0], d), q1 = rdlane(qr[1], d);
            float q2 = rdlane(qr[2], d), q3 = rdlane(qr[3], d);
            float kv0 = kT[d][lane], kv1 = kT[d][lane + 64], kv2 = kT[d][lane + 128];
            float kv3 = v3 ? kT[d][lane + 192] : 0.0f;
            x[0][0] = fmaf(q0, kv0, x[0][0]); x[0][1] = fmaf(q0, kv1, x[0][1]);
            x[0][2] = fmaf(q0, kv2, x[0][2]); x[0][3] = fmaf(q0, kv3, x[0][3]);
            x[1][0] = fmaf(q1, kv0, x[1][0]); x[1][1] = fmaf(q1, kv1, x[1][1]);
            x[1][2] = fmaf(q1, kv2, x[1][2]); x[1][3] = fmaf(q1, kv3, x[1][3]);
            x[2][0] = fmaf(q2, kv0, x[2][0]); x[2][1] = fmaf(q2, kv1, x[2][1]);
            x[2][2] = fmaf(q2, kv2, x[2][2]); x[2][3] = fmaf(q2, kv3, x[2][3]);
            x[3][0] = fmaf(q3, kv0, x[3][0]); x[3][1] = fmaf(q3, kv1, x[3][1]);
            x[3][2] = fmaf(q3, kv2, x[3][2]); x[3][3] = fmaf(q3, kv3, x[3][3]);
          }
        }
        // center / RNG rows (t < 61) overwrite
#pragma unroll
        for (int i = 0; i < 4; i++) {
          const int t = t0 + i;
          if (t >= 61) continue;
          if (t == 0) {
            x[0][0] = cen[lane]; x[0][1] = cen[lane + 64]; x[0][2] = cen[lane + 128];
            x[0][3] = v3 ? cen[lane + 192] : 0.0f;
          } else {
            const int ns = t - 1;
            const uint32_t base = ((uint32_t)ns * 1536u + (uint32_t)b) * 197u;
            float r0 = u01f(rbits(k1a, k1b, base + lane))       * 2.0f - 1.0f;
            float r1 = u01f(rbits(k1a, k1b, base + lane + 64))  * 2.0f - 1.0f;
            float r2 = u01f(rbits(k1a, k1b, base + lane + 128)) * 2.0f - 1.0f;
            float r3 = v3 ? (u01f(rbits(k1a, k1b, base + lane + 192)) * 2.0f - 1.0f) : 0.0f;
            float pa = r0 * us0 + r1 * us1 + r2 * us2 + r3 * us3;
#pragma unroll
            for (int off = 32; off >= 1; off >>= 1) pa += __shfl_xor(pa, off, 64);
            float rp0 = r0 - pa * us0, rp1 = r1 - pa * us1;
            float rp2 = r2 - pa * us2, rp3 = r3 - pa * us3;
            float sq2 = rp0 * rp0 + rp1 * rp1 + rp2 * rp2 + (v3 ? rp3 * rp3 : 0.0f);
#pragma unroll
            for (int off = 32; off >= 1; off >>= 1) sq2 += __shfl_xor(sq2, off, 64);
            float invn = 1.0f / fmaxf(sqrtf(sq2), EPSc);
            float cv = u01f(rbits(k2a, k2b, (uint32_t)ns)) * 0.2f + 0.7f;
            float sv = sqrtf(1.0f - cv * cv);
            float f = sv * invn;
            x[i][0] = cnb * (cv * us0 + f * rp0);
            x[i][1] = cnb * (cv * us1 + f * rp1);
            x[i][2] = cnb * (cv * us2 + f * rp2);
            x[i][3] = cnb * (cv * us3 + f * rp3);
          }
        }
        float pr[4][4];
        softmax4(x, v3, pr);
#pragma unroll
        for (int i = 0; i < 4; i++)
          if (c < 8 || i == 0) weights_add(awn, t0 + i, lane, v3, pr[i]);
        // P -> LDS (bf16 RNE); buffer c&1, slot = w*4+i
#pragma unroll
        for (int i = 0; i < 4; i++) {
          unsigned short* pRow = &Pl[c & 1][(w * 4 + i) * 232];
          pRow[lane]       = bf16rne(pr[i][0]);
          pRow[lane + 64]  = bf16rne(pr[i][1]);
          pRow[lane + 128] = bf16rne(pr[i][2]);
          if (v3) pRow[lane + 192] = bf16rne(pr[i][3]);
        }
      }
    }

    // ---- PV phase for chunk c-1 (same phase, other Pl buffer) ----
    if (c >= 1) {
      const int cc = c - 1;
      const bool pvact = (cc < 8) || (w < 4);
      if (pvact) {
        const int tt = (cc < 8) ? (w >> 2) : 0;
        const int dj = (cc < 8) ? (w & 3) : w;
        accfrag_t acc = {0.0f, 0.0f, 0.0f, 0.0f};
        const unsigned short* pA = &Pl[cc & 1][(tt * 16 + l16) * 232] + q4 * 8;
        const unsigned short* pH = Vth + (dj * 16 + l16) * 232 + q4 * 8;
        const unsigned short* pL = Vtl + (dj * 16 + l16) * 232 + q4 * 8;
#pragma unroll
        for (int ks = 0; ks < 7; ks++) {
          bfrag_t af = *(const bfrag_t*)(pA + ks * 32);
          bfrag_t bh = *(const bfrag_t*)(pH + ks * 32);
          bfrag_t bl = *(const bfrag_t*)(pL + ks * 32);
          acc = __builtin_amdgcn_mfma_f32_16x16x32_bf16(af, bh, acc, 0, 0, 0);
          acc = __builtin_amdgcn_mfma_f32_16x16x32_bf16(af, bl, acc, 0, 0, 0);
        }
        const int tbase = cc * 32 + tt * 16 + q4 * 4;
        const int d = dj * 16 + l16;
#pragma unroll
        for (int r = 0; r < 4; r++) {
          const int t = tbase + r;
          if (t <= 256) {
            unsigned short hb, lb;
            f2hilo(acc[r], hb, lb);
            size_t base = ((size_t)t * 128 + n) * 1536 + h * 64 + d;
            A2[base] = hb;
            A2[base + 768] = lb;
          }
        }
      }
    }
    if (c < 9) __syncthreads();
  }
}

// ---------------- launch ----------------
extern "C" void kernel_launch(void* const* d_in, const int* in_sizes, int n_in,
                              void* d_out, int out_size, void* d_ws, size_t ws_size,
                              hipStream_t stream)
{
  const float* query = (const float*)d_in[0];
  const float* key   = (const float*)d_in[1];
  const float* value = (const float*)d_in[2];
  const float* w_in  = (const float*)d_in[3];
  const float* b_in  = (const float*)d_in[4];
  const float* w_out = (const float*)d_in[5];
  const float* b_out = (const float*)d_in[6];

  float* out    = (float*)d_out;                       // (257,128,768)
  float* attn_w = out + (size_t)LTc * Nc * Ec;         // (128,257,197)

  // ---- workspace layout (bytes) ----
  constexpr size_t SZ_HEADF = (size_t)Bc * Lc * HDc * 4;   // 77,463,552 per fp32 head buf
  constexpr size_t OFF_CEN  = 3 * SZ_HEADF;
  constexpr size_t OFF_CN   = OFF_CEN + (size_t)Bc * Lc * 4;
  constexpr size_t R0       = OFF_CN + 8192;               // reusable region start
  constexpr size_t SZ_XB    = (size_t)25216 * 1536 * 2;    // 77,463,552 per bf16 input
  constexpr size_t SZ_A2    = (size_t)LTc * Nc * 1536 * 2; // 101,056,512
  constexpr size_t SZ_WB    = (size_t)2304 * 1536 * 2;     // 7,077,888
  constexpr size_t SZ_WOB   = (size_t)768 * 1536 * 2;      // 2,359,296
  constexpr size_t FULL_NEED = R0 + 3 * SZ_XB + SZ_WB + SZ_WOB;   // ~475.4 MB

  uint8_t* w8 = (uint8_t*)d_ws;
  float* q_ws   = (float*)w8;
  float* k_ws   = (float*)(w8 + SZ_HEADF);
  float* v_ws   = (float*)(w8 + 2 * SZ_HEADF);
  float* center = (float*)(w8 + OFF_CEN);
  float* cnorm  = (float*)(w8 + OFF_CN);
  unsigned short* A2b = (unsigned short*)(w8 + R0);        // lives during attn..gemm2

  const bool full = ws_size >= FULL_NEED;
  unsigned short* wb  = (unsigned short*)(w8 + (full ? (R0 + 3 * SZ_XB) : (R0 + SZ_XB)));
  unsigned short* wob = (unsigned short*)(w8 + (full ? (R0 + 3 * SZ_XB + SZ_WB) : (R0 + SZ_A2)));

  (void)in_sizes; (void)n_in; (void)out_size;

  // weight conversions (tiny)
  convert_hilo<<<(2304 * 192 + 255) / 256, 256, 0, stream>>>(w_in, wb, 2304);
  convert_hilo<<<(768 * 192 + 255) / 256, 256, 0, stream>>>(w_out, wob, 768);

  const int xblk = (25216 * 192 + 255) / 256;
  if (full) {
    unsigned short* xb0 = (unsigned short*)(w8 + R0);
    unsigned short* xb1 = xb0 + SZ_XB / 2;
    unsigned short* xb2 = xb1 + SZ_XB / 2;
    convert_hilo<<<xblk, 256, 0, stream>>>(query, xb0, 25216);
    convert_hilo<<<xblk, 256, 0, stream>>>(key,   xb1, 25216);
    convert_hilo<<<xblk, 256, 0, stream>>>(value, xb2, 25216);
    gemm_mfma<0><<<dim3(197, 18), 256, 0, stream>>>(xb0, xb1, xb2, wb, b_in, 0,
                                                    q_ws, k_ws, v_ws);
  } else {
    unsigned short* buf = (unsigned short*)(w8 + R0);
    const float* xs[3] = {query, key, value};
    for (int wh = 0; wh < 3; wh++) {
      convert_hilo<<<xblk, 256, 0, stream>>>(xs[wh], buf, 25216);
      gemm_mfma<0><<<dim3(197, 6), 256, 0, stream>>>(buf, buf, buf, wb, b_in, 6 * wh,
                                                     q_ws, k_ws, v_ws);
    }
  }

  center_kernel<<<dim3(1536), 256, 0, stream>>>(q_ws, k_ws, center, cnorm);

  // attn_weights accumulated atomically -> zero it (d_out is poisoned 0xAA)
  hipMemsetAsync(attn_w, 0, (size_t)Nc * LTc * Lc * sizeof(float), stream);

  attn_kernel<<<dim3(1536), 512, 0, stream>>>(q_ws, k_ws, v_ws, center, cnorm,
                                              A2b, attn_w);

  gemm_mfma<1><<<dim3(257, 6), 256, 0, stream>>>(A2b, nullptr, nullptr, wob, b_out, 0,
                                                 out, nullptr, nullptr);
}